// Round 8
// baseline (210.102 us; speedup 1.0000x reference)
//
#include <hip/hip_runtime.h>

typedef unsigned int u32;
typedef int i32x4 __attribute__((ext_vector_type(4)));

#define DIN 2048              // K elements; int8 row = 2048 bytes
#define DOUT 8192
#define MROWS 8192            // B*S
#define NELEM_W (8192 * 2048)
#define NT 16                 // K-tiles of 128 int8

// workspace layout (bytes)
#define WS_PART 0                        // double[2048]
#define WS_WFAC 16384                    // float
#define WS_ROWFAC 16640                  // float[8192]
#define WS_XQ 49408                      // int8[8192*2048]
#define WS_WQ (49408 + 16777216)         // int8[8192*2048]

// ---------------- weight abs-sum (stage 1) ----------------------------------
__global__ void k_wabs(const float* __restrict__ w, double* __restrict__ part) {
    const float4* w4 = (const float4*)w;
    const unsigned t = threadIdx.x, b = blockIdx.x;
    float s = 0.f;
    for (unsigned i = b * 256u + t; i < (NELEM_W / 4); i += 2048u * 256u) {
        float4 v = w4[i];
        s += fabsf(v.x) + fabsf(v.y) + fabsf(v.z) + fabsf(v.w);
    }
    double d = (double)s;
    #pragma unroll
    for (int o = 32; o; o >>= 1) d += __shfl_down(d, o);
    __shared__ double red[4];
    if ((t & 63u) == 0u) red[t >> 6] = d;
    __syncthreads();
    if (t == 0) part[b] = red[0] + red[1] + red[2] + red[3];
}

// ---------------- weight abs-mean (stage 2) ---------------------------------
__global__ void k_wfin(const double* __restrict__ part, float* __restrict__ wfac) {
    const int t = threadIdx.x;
    double s = 0.0;
    #pragma unroll
    for (int j = 0; j < 8; ++j) s += part[t + j * 256];
    #pragma unroll
    for (int o = 32; o; o >>= 1) s += __shfl_down(s, o);
    __shared__ double red[4];
    if ((t & 63) == 0) red[t >> 6] = s;
    __syncthreads();
    if (t == 0) {
        double mean = (red[0] + red[1] + red[2] + red[3]) * (1.0 / (double)NELEM_W);
        *wfac = fmaxf((float)mean, 1e-5f);
    }
}

// ---------------- fused: ternary weight quant + RMS-norm/act quant ----------
__global__ void k_prep(const float* __restrict__ w, const float* __restrict__ wfac,
                       u32* __restrict__ wq, const float* __restrict__ x,
                       u32* __restrict__ xq, float* __restrict__ rowfac) {
    const int t = threadIdx.x;
    if (blockIdx.x < 2048) {
        const float scale = 1.0f / *wfac;
        const float4* w4 = (const float4*)w;
        for (unsigned i = blockIdx.x * 256u + t; i < (NELEM_W / 4); i += 2048u * 256u) {
            float4 v = w4[i];
            int q0 = (int)fminf(fmaxf(rintf(v.x * scale), -1.f), 1.f);
            int q1 = (int)fminf(fmaxf(rintf(v.y * scale), -1.f), 1.f);
            int q2 = (int)fminf(fmaxf(rintf(v.z * scale), -1.f), 1.f);
            int q3 = (int)fminf(fmaxf(rintf(v.w * scale), -1.f), 1.f);
            wq[i] = (u32)(q0 & 255) | ((u32)(q1 & 255) << 8) |
                    ((u32)(q2 & 255) << 16) | ((u32)(q3 & 255) << 24);
        }
        return;
    }
    const int row = blockIdx.x - 2048;
    const float4* xr = (const float4*)(x + (size_t)row * DIN);
    float4 v0 = xr[t], v1 = xr[t + 256];
    float ss = v0.x * v0.x + v0.y * v0.y + v0.z * v0.z + v0.w * v0.w
             + v1.x * v1.x + v1.y * v1.y + v1.z * v1.z + v1.w * v1.w;
    __shared__ float red[4];
    #pragma unroll
    for (int o = 32; o; o >>= 1) ss += __shfl_down(ss, o);
    if ((t & 63) == 0) red[t >> 6] = ss;
    __syncthreads();
    ss = red[0] + red[1] + red[2] + red[3];
    const float r = 1.0f / sqrtf(ss * (1.0f / DIN) + 1.1920929e-7f);
    float xn[8] = {v0.x * r, v0.y * r, v0.z * r, v0.w * r,
                   v1.x * r, v1.y * r, v1.z * r, v1.w * r};
    float am = 0.f;
    #pragma unroll
    for (int j = 0; j < 8; ++j) am = fmaxf(am, fabsf(xn[j]));
    __syncthreads();
    #pragma unroll
    for (int o = 32; o; o >>= 1) am = fmaxf(am, __shfl_down(am, o));
    if ((t & 63) == 0) red[t >> 6] = am;
    __syncthreads();
    am = fmaxf(fmaxf(red[0], red[1]), fmaxf(red[2], red[3]));
    const float amc = fmaxf(am, 1e-5f);
    const float s = 127.0f / amc;
    int q[8];
    #pragma unroll
    for (int j = 0; j < 8; ++j)
        q[j] = (int)fminf(fmaxf(rintf(xn[j] * s), -128.f), 127.f);
    u32* xo = xq + (size_t)row * (DIN / 4);
    xo[t] = (u32)(q[0] & 255) | ((u32)(q[1] & 255) << 8) |
            ((u32)(q[2] & 255) << 16) | ((u32)(q[3] & 255) << 24);
    xo[t + 256] = (u32)(q[4] & 255) | ((u32)(q[5] & 255) << 8) |
                  ((u32)(q[6] & 255) << 16) | ((u32)(q[7] & 255) << 24);
    if (t == 0) rowfac[row] = amc * (1.0f / 127.0f);
}

// ---------------- persistent 256x256 int8 GEMM (r3 inner loop) ---------------
// Grid = 256 blocks (1/CU). Each block computes 4 output tiles (2x2 zigzag
// super-tile); XCD-partitioned bm-ranges keep A panels L2-resident per XCD.
// Inner K-loop = round-3's proven structure: 4 phases/tile, STAGE 1 half-tile
// per phase, VM(4) twice per tile, raw barriers, zero bank conflicts.
// Epilogue stores issued with NO wait: the next tile's prologue VM(4) drains
// them after they've had the staging phase to fly (stores count in vmcnt).
__launch_bounds__(512, 2)
__global__ void k_gemm(const char* __restrict__ A, const char* __restrict__ Bw,
                       const float* __restrict__ rowfac, const float* __restrict__ wfac,
                       float* __restrict__ out) {
    __shared__ __attribute__((aligned(16))) char smb[131072]; // A[2 slot][2 kh][256][64B], B @ +65536

    const int t = threadIdx.x;
    const int l = t & 63, w = t >> 6;
    const int wm = w >> 2, wn = w & 3;
    const int lr = l & 15, lc = l >> 4;
    // r3's verified zero-conflict swizzled read offset within [256][64B] half-buffer
    const int laneF = lr * 64 + ((lc ^ ((lr >> 1) & 3)) * 16);

    // persistent tile mapping: block -> XCD-contiguous super-tile
    const int bid = blockIdx.x;            // 0..255
    const int xcd = bid & 7, idx = bid >> 3;
    const int st = xcd * 32 + idx;         // bijective, XCD-contiguous
    const int sm = st >> 4, sn = st & 15;  // super-tile coords (16x16)

    const float wf = *wfac;

#define STAGE(gbase, opOff, tt, kh) do {                                          \
    _Pragma("unroll")                                                             \
    for (int j_ = 0; j_ < 2; ++j_) {                                              \
        const int seg_ = w * 2 + j_;                                              \
        const int row_ = seg_ * 16 + (l >> 2);                                    \
        const int sc_ = (l & 3) ^ ((l >> 3) & 3);                                 \
        const char* src_ = (gbase) + (size_t)row_ * DIN + (tt) * 128 + (kh) * 64 + sc_ * 16; \
        __builtin_amdgcn_global_load_lds(                                         \
            (const __attribute__((address_space(1))) void*)src_,                  \
            (__attribute__((address_space(3))) void*)(smb + (opOff) + ((tt) & 1) * 32768 + (kh) * 16384 + seg_ * 1024), \
            16, 0, 0);                                                            \
    }                                                                             \
} while (0)

#define PHASE_MFMA(MBASE)                                                         \
    __builtin_amdgcn_s_barrier();                                                 \
    __builtin_amdgcn_s_setprio(1);                                                \
    _Pragma("unroll")                                                             \
    for (int i = 0; i < 4; ++i)                                                   \
        _Pragma("unroll")                                                         \
        for (int n = 0; n < 4; ++n)                                               \
            acc[(MBASE) + i][n] = __builtin_amdgcn_mfma_i32_16x16x64_i8(          \
                afr[i], bfr[n], acc[(MBASE) + i][n], 0, 0, 0);                    \
    __builtin_amdgcn_s_setprio(0);                                                \
    __builtin_amdgcn_s_barrier();

    #pragma unroll 1
    for (int j = 0; j < 4; ++j) {
        // zigzag within the 2x2 super-tile: (0,0)->(0,1)->(1,1)->(1,0)
        const int bm = sm * 2 + (j >> 1);
        const int bn = sn * 2 + ((j & 1) ^ (j >> 1));
        const char* Ab = A + (size_t)(bm * 256) * DIN;
        const char* Bb = Bw + (size_t)(bn * 256) * DIN;

        i32x4 acc[8][4] = {};

        // prologue: stage tile 0; VM(4) also drains the previous tile's
        // C-stores (they were issued before these 8 loads)
        STAGE(Ab, 0,     0, 0);
        STAGE(Bb, 65536, 0, 0);
        STAGE(Ab, 0,     0, 1);
        STAGE(Bb, 65536, 0, 1);
        asm volatile("s_waitcnt vmcnt(4)" ::: "memory");
        __builtin_amdgcn_s_barrier();

        #pragma unroll 1
        for (int kt = 0; kt < NT; ++kt) {
            const int AB = (kt & 1) * 32768;
            const bool more = (kt < NT - 1);
            const char* aBase = smb + AB;
            const char* bBase = smb + 65536 + AB;
            i32x4 afr[4], bfr[4];

            // ---- phase 0: kh=0, m0-3 ----
            #pragma unroll
            for (int n = 0; n < 4; ++n)
                bfr[n] = *(const i32x4*)(bBase + (wn * 64 + n * 16) * 64 + laneF);
            #pragma unroll
            for (int i = 0; i < 4; ++i)
                afr[i] = *(const i32x4*)(aBase + (wm * 128 + i * 16) * 64 + laneF);
            if (more) STAGE(Ab, 0, kt + 1, 0);
            PHASE_MFMA(0)

            // ---- phase 1: kh=0, m4-7 (bfr reused) ----
            #pragma unroll
            for (int i = 0; i < 4; ++i)
                afr[i] = *(const i32x4*)(aBase + (wm * 128 + (4 + i) * 16) * 64 + laneF);
            if (more) {
                STAGE(Bb, 65536, kt + 1, 0);
                asm volatile("s_waitcnt vmcnt(4)" ::: "memory");
            } else {
                asm volatile("s_waitcnt vmcnt(0)" ::: "memory");
            }
            PHASE_MFMA(4)

            // ---- phase 2: kh=1, m0-3 ----
            #pragma unroll
            for (int n = 0; n < 4; ++n)
                bfr[n] = *(const i32x4*)(bBase + 16384 + (wn * 64 + n * 16) * 64 + laneF);
            #pragma unroll
            for (int i = 0; i < 4; ++i)
                afr[i] = *(const i32x4*)(aBase + 16384 + (wm * 128 + i * 16) * 64 + laneF);
            if (more) STAGE(Ab, 0, kt + 1, 1);
            PHASE_MFMA(0)

            // ---- phase 3: kh=1, m4-7 ----
            #pragma unroll
            for (int i = 0; i < 4; ++i)
                afr[i] = *(const i32x4*)(aBase + 16384 + (wm * 128 + (4 + i) * 16) * 64 + laneF);
            if (more) {
                STAGE(Bb, 65536, kt + 1, 1);
                asm volatile("s_waitcnt vmcnt(4)" ::: "memory");
            }
            PHASE_MFMA(4)
        }

        // epilogue: exact int32 -> fp32, dequant, store — fire and forget.
        // Next tile's prologue VM(4) drains these after staging has flown.
        const int c0 = bn * 256 + wn * 64 + lr;
        #pragma unroll
        for (int m = 0; m < 8; ++m) {
            #pragma unroll
            for (int r = 0; r < 4; ++r) {
                const int grow = bm * 256 + wm * 128 + m * 16 + lc * 4 + r;
                const float s = rowfac[grow] * wf;
                const size_t ob = (size_t)grow * DOUT + c0;
                #pragma unroll
                for (int n = 0; n < 4; ++n)
                    out[ob + n * 16] = (float)acc[m][n][r] * s;
            }
        }
    }
#undef STAGE
#undef PHASE_MFMA
}

extern "C" void kernel_launch(void* const* d_in, const int* in_sizes, int n_in,
                              void* d_out, int out_size, void* d_ws, size_t ws_size,
                              hipStream_t stream) {
    const float* x = (const float*)d_in[0];   // [4,2048,2048]
    const float* wt = (const float*)d_in[1];  // [8192,2048]
    float* out = (float*)d_out;               // [4,2048,8192] fp32
    char* ws = (char*)d_ws;

    double* part = (double*)(ws + WS_PART);
    float* wfac = (float*)(ws + WS_WFAC);
    float* rowfac = (float*)(ws + WS_ROWFAC);
    u32* xq = (u32*)(ws + WS_XQ);
    u32* wq = (u32*)(ws + WS_WQ);

    k_wabs<<<2048, 256, 0, stream>>>(wt, part);
    k_wfin<<<1, 256, 0, stream>>>(part, wfac);
    k_prep<<<2048 + MROWS, 256, 0, stream>>>(wt, wfac, wq, x, xq, rowfac);
    k_gemm<<<256, 512, 0, stream>>>((const char*)xq, (const char*)wq, rowfac, wfac, out);
}